// Round 10
// baseline (101.096 us; speedup 1.0000x reference)
//
#include <hip/hip_runtime.h>
#include <cstddef>

#define ALPHA 0.2f
constexpr int B = 2, N = 8192, F = 256, D = 128;
constexpr int M = B * N;
constexpr int NB = 2048;          // value buckets per batch
constexpr int SUB = 128;          // elements per sub-block for stable scatter
constexpr int P = N / SUB;        // 64 sub-blocks per batch
constexpr int GB = 2;             // buckets per k_bsum block
constexpr int NBB = NB / GB;      // 1024 bsum blocks per batch
constexpr int GSZ = 32;           // buckets per scan group
constexpr int NGRP = NB / GSZ;    // 64 groups per batch
constexpr int QROWS = 8;          // rows per k_query block
constexpr int DSL = 4;            // d's per k_scan slice
constexpr int NSL = D / DSL;      // 32 slices

typedef __attribute__((ext_vector_type(8))) short bf16x8;
typedef __attribute__((ext_vector_type(4))) float f32x4;

// ---- fixed monotone bucket map (correct for ANY input via clamping) ----
#define BMIN (-10.0f)
#define BSCALE ((float)NB / 20.0f)
__device__ inline int bucket_of(float x) {
  int g = (int)((x - BMIN) * BSCALE);
  return g < 0 ? 0 : (g > NB - 1 ? NB - 1 : g);
}

__device__ inline unsigned short bf16_rne(float x) {
  unsigned u = __float_as_uint(x);
  return (unsigned short)((u + 0x7FFFu + ((u >> 16) & 1u)) >> 16);
}
__device__ inline float bf16_tof(unsigned short h) {
  return __uint_as_float(((unsigned)h) << 16);
}

// ---------------- MFMA split-bf16 GEMM + fused f1/f2 epilogue ----------------
// A,B split hi/lo bf16; C = Ah*Bh + Al*Bh + Ah*Bl (exact to ~2^-16 rel).
// Self-consistent contiguous-8 k-map for A and B fragments (permutation-invariant).
__global__ __launch_bounds__(512) void k_gemm(const float* __restrict__ seq,
                                              const float* __restrict__ Wf,
                                              const float* __restrict__ w1,
                                              const float* __restrict__ b1,
                                              const float* __restrict__ w2,
                                              const float* __restrict__ b2,
                                              float* __restrict__ fts,
                                              float* __restrict__ f1,
                                              float* __restrict__ f2) {
  __shared__ unsigned short Ah[64][40], Al[64][40];     // [row][k], 80B rows (16B-aligned frags)
  __shared__ unsigned short Bh[128][40], Bl[128][40];   // [col][k] (transposed)
  __shared__ float part1[64][2], part2[64][2];
  const int m0 = blockIdx.x * 64;
  const int t = threadIdx.x;
  const int w = t >> 6;                 // wave 0..7
  const int lane = t & 63;
  const int q = lane >> 4, rt = lane & 15;
  const int r0 = (w & 3) * 16;          // wave's 16-row group
  const int c0 = (w >> 2) * 64;         // wave's 64-col group
  f32x4 acc[4];
#pragma unroll
  for (int ct = 0; ct < 4; ++ct) acc[ct] = (f32x4){0.f, 0.f, 0.f, 0.f};

  for (int kc = 0; kc < F; kc += 32) {
    {  // stage A 64x32: one float4 per thread -> hi/lo bf16
      const int row = t >> 3, k4 = t & 7;
      const float4 v = *reinterpret_cast<const float4*>(
          &seq[(size_t)(m0 + row) * F + kc + k4 * 4]);
      const float vv[4] = {v.x, v.y, v.z, v.w};
#pragma unroll
      for (int i = 0; i < 4; ++i) {
        const unsigned short h = bf16_rne(vv[i]);
        Ah[row][k4 * 4 + i] = h;
        Al[row][k4 * 4 + i] = bf16_rne(vv[i] - bf16_tof(h));
      }
    }
#pragma unroll
    for (int it = 0; it < 2; ++it) {  // stage B 32x128 transposed -> [col][k]
      const int f = t + it * 512;
      const int kr = f >> 5, c4 = f & 31;
      const float4 v = *reinterpret_cast<const float4*>(
          &Wf[(size_t)(kc + kr) * D + c4 * 4]);
      const float vv[4] = {v.x, v.y, v.z, v.w};
#pragma unroll
      for (int i = 0; i < 4; ++i) {
        const unsigned short h = bf16_rne(vv[i]);
        Bh[c4 * 4 + i][kr] = h;
        Bl[c4 * 4 + i][kr] = bf16_rne(vv[i] - bf16_tof(h));
      }
    }
    __syncthreads();
    const bf16x8 ah = *reinterpret_cast<const bf16x8*>(&Ah[r0 + rt][q * 8]);
    const bf16x8 al = *reinterpret_cast<const bf16x8*>(&Al[r0 + rt][q * 8]);
#pragma unroll
    for (int ct = 0; ct < 4; ++ct) {
      const bf16x8 bh = *reinterpret_cast<const bf16x8*>(&Bh[c0 + ct * 16 + rt][q * 8]);
      const bf16x8 bl = *reinterpret_cast<const bf16x8*>(&Bl[c0 + ct * 16 + rt][q * 8]);
      acc[ct] = __builtin_amdgcn_mfma_f32_16x16x32_bf16(ah, bh, acc[ct], 0, 0, 0);
      acc[ct] = __builtin_amdgcn_mfma_f32_16x16x32_bf16(al, bh, acc[ct], 0, 0, 0);
      acc[ct] = __builtin_amdgcn_mfma_f32_16x16x32_bf16(ah, bl, acc[ct], 0, 0, 0);
    }
    __syncthreads();
  }
  // store fts: C layout col=lane&15, row=(lane>>4)*4+reg  [m89-verified]
#pragma unroll
  for (int ct = 0; ct < 4; ++ct)
#pragma unroll
    for (int reg = 0; reg < 4; ++reg)
      fts[(size_t)(m0 + r0 + q * 4 + reg) * D + c0 + ct * 16 + rt] = acc[ct][reg];

  // fused f1/f2: per-wave partial dots, cross-wave combine via LDS
#pragma unroll
  for (int reg = 0; reg < 4; ++reg) {
    float s1 = 0.f, s2 = 0.f;
#pragma unroll
    for (int ct = 0; ct < 4; ++ct) {
      const int c = c0 + ct * 16 + rt;
      s1 += acc[ct][reg] * w1[c];
      s2 += acc[ct][reg] * w2[c];
    }
#pragma unroll
    for (int off = 8; off > 0; off >>= 1) {
      s1 += __shfl_down(s1, off, 16);
      s2 += __shfl_down(s2, off, 16);
    }
    if (rt == 0) {
      part1[r0 + q * 4 + reg][w >> 2] = s1;
      part2[r0 + q * 4 + reg][w >> 2] = s2;
    }
  }
  __syncthreads();
  if (t < 64) {
    f1[m0 + t] = part1[t][0] + part1[t][1] + b1[0];
    f2[m0 + t] = part2[t][0] + part2[t][1] + b2[0];
  }
}

// ---------------- per-sub-block histogram (deterministic) ----------------
__global__ __launch_bounds__(128) void k_hist(const float* __restrict__ f2,
                                              int* __restrict__ bid,
                                              int* __restrict__ histcnt) {
  __shared__ int hist[NB];
  const int b = blockIdx.x / P, p = blockIdx.x % P;
  const int t = threadIdx.x;
  for (int i = t; i < NB; i += 128) hist[i] = 0;
  const int j = p * SUB + t;
  float x = f2[b * N + j];
  int g = bucket_of(x);
  bid[b * N + j] = g;
  __syncthreads();
  atomicAdd(&hist[g], 1);
  __syncthreads();
  for (int i = t; i < NB; i += 128)
    histcnt[((size_t)(b * P + p)) * NB + i] = hist[i];
}

// ---------------- per-bucket prefix over sub-blocks + bucket totals ----------------
__global__ __launch_bounds__(256) void k_sub(const int* __restrict__ histcnt,
                                             int* __restrict__ substart,
                                             int* __restrict__ btot) {
  const int gid = blockIdx.x * 256 + threadIdx.x;  // 0 .. B*NB-1
  const int b = gid / NB, g = gid % NB;
  int run = 0;
  for (int pp = 0; pp < P; ++pp) {
    substart[((size_t)(b * P + pp)) * NB + g] = run;
    run += histcnt[((size_t)(b * P + pp)) * NB + g];
  }
  btot[b * NB + g] = run;
}

// ---------------- scatter of keys/weights (local bucket scan from btot) ----------------
__global__ __launch_bounds__(128) void k_scat(const float* __restrict__ f2,
                                              const int* __restrict__ bid,
                                              const int* __restrict__ substart,
                                              const int* __restrict__ btot,
                                              int* __restrict__ bstart,
                                              float* __restrict__ f2s,
                                              int* __restrict__ idxs,
                                              float* __restrict__ wps,
                                              float* __restrict__ wns) {
  __shared__ int bstart_lds[NB];
  __shared__ int bids[SUB];
  __shared__ int wsum2[2];
  const int b = blockIdx.x / P, p = blockIdx.x % P;
  const int t = threadIdx.x;
  const int lane = t & 63, wave = t >> 6;
  const size_t bN = (size_t)b * N;

  int c[16];
  int loc = 0;
#pragma unroll
  for (int i = 0; i < 16; ++i) { c[i] = btot[b * NB + t * 16 + i]; loc += c[i]; }
  int incl = loc;
#pragma unroll
  for (int off = 1; off < 64; off <<= 1) {
    int y = __shfl_up(incl, off);
    if (lane >= off) incl += y;
  }
  if (lane == 63) wsum2[wave] = incl;
  __syncthreads();
  if (wave == 1) incl += wsum2[0];
  int excl = incl - loc;
#pragma unroll
  for (int i = 0; i < 16; ++i) { bstart_lds[t * 16 + i] = excl; excl += c[i]; }
  __syncthreads();
  if (p == 0) {
    for (int i = t; i < NB; i += 128) bstart[b * (NB + 1) + i] = bstart_lds[i];
    if (t == 0) bstart[b * (NB + 1) + NB] = N;
  }

  const int j = p * SUB + t;
  const int g = bid[bN + j];
  bids[t] = g;
  __syncthreads();
  int off = bstart_lds[g] + substart[((size_t)(b * P + p)) * NB + g];
  for (int jj = 0; jj < t; ++jj) off += (bids[jj] == g);
  const float x = f2[bN + j];
  f2s[bN + off] = x;
  idxs[bN + off] = j;
  wps[bN + off] = expf(x);
  wns[bN + off] = expf(ALPHA * x);
}

// ---------------- permute fts into scattered order (full-grid gather) ----------------
__global__ __launch_bounds__(256) void k_perm(const float* __restrict__ fts,
                                              const int* __restrict__ idxs,
                                              float* __restrict__ fts_s) {
  const int tid = blockIdx.x * 256 + threadIdx.x;    // one float4 each
  const int eg = tid >> 5;                           // global scattered row (b*N+e)
  const int q = tid & 31;
  const int b = eg / N;
  const int j = idxs[eg];
  *reinterpret_cast<float4*>(&fts_s[(size_t)eg * D + q * 4]) =
      *reinterpret_cast<const float4*>(&fts[((size_t)b * N + j) * D + q * 4]);
}

// ---------------- per-bucket weighted sums (streaming, high TLP) ----------------
__global__ __launch_bounds__(128) void k_bsum(const float* __restrict__ fts_s,
                                              const float* __restrict__ wps,
                                              const float* __restrict__ wns,
                                              const int* __restrict__ bstart,
                                              float* __restrict__ Wp, float* __restrict__ Wn,
                                              float* __restrict__ Cp, float* __restrict__ Cn) {
  const int b = blockIdx.x / NBB, blk = blockIdx.x % NBB;
  const int d = threadIdx.x;
  const int gbase = blk * GB;
  const size_t bN = (size_t)b * N;
  for (int gg = 0; gg < GB; ++gg) {
    const int g = gbase + gg;
    const int e0 = bstart[b * (NB + 1) + g], e1 = bstart[b * (NB + 1) + g + 1];
    float ap = 0.f, an = 0.f, sp = 0.f, sn = 0.f;
    int e = e0;
    for (; e + 4 <= e1; e += 4) {
      const float* vp = &fts_s[(bN + e) * D + d];
      const float v0 = vp[0], v1 = vp[D], v2 = vp[2 * D], v3 = vp[3 * D];
      const float p0 = wps[bN + e], p1 = wps[bN + e + 1], p2 = wps[bN + e + 2], p3 = wps[bN + e + 3];
      const float n0 = wns[bN + e], n1 = wns[bN + e + 1], n2 = wns[bN + e + 2], n3 = wns[bN + e + 3];
      ap += p0 * v0 + p1 * v1 + p2 * v2 + p3 * v3;
      an += n0 * v0 + n1 * v1 + n2 * v2 + n3 * v3;
      sp += p0 + p1 + p2 + p3;
      sn += n0 + n1 + n2 + n3;
    }
    for (; e < e1; ++e) {
      const float v = fts_s[(bN + e) * D + d];
      const float wp = wps[bN + e], wn = wns[bN + e];
      ap += wp * v; an += wn * v; sp += wp; sn += wn;
    }
    Wp[((size_t)b * NB + g) * D + d] = ap;
    Wn[((size_t)b * NB + g) * D + d] = an;
    if (d == 0) { Cp[b * NB + g] = sp; Cn[b * NB + g] = sn; }
  }
}

// ---------------- fused 3-phase bucket-boundary scan (GSZ=32 rebalance) ----------------
__global__ __launch_bounds__(256) void k_scan(const float* __restrict__ Wp, const float* __restrict__ Wn,
                                              const float* __restrict__ Cp, const float* __restrict__ Cn,
                                              float* __restrict__ BPos, float* __restrict__ BNeg,
                                              float* __restrict__ CpB, float* __restrict__ CnB) {
  __shared__ float gp[NGRP][DSL], gn[NGRP][DSL];
  __shared__ float cgp[NGRP], cgn[NGRP];
  const int b = blockIdx.x / NSL, sl = blockIdx.x % NSL;
  const int t = threadIdx.x;                 // 256 = NGRP(64) x DSL(4)
  const int d4 = t & (DSL - 1), grp = t >> 2;
  const int d = sl * DSL + d4;
  const size_t base = (size_t)b * NB;

  float sp = 0.f, sn = 0.f;
  for (int gg = 0; gg < GSZ; ++gg) {
    const int g = grp * GSZ + gg;
    sp += Wp[(base + g) * D + d];
    sn += Wn[(base + g) * D + d];
  }
  gp[grp][d4] = sp; gn[grp][d4] = sn;
  if (sl == 0 && d4 == 0) {
    float cp = 0.f, cn = 0.f;
    for (int gg = 0; gg < GSZ; ++gg) { const int g = grp * GSZ + gg; cp += Cp[base + g]; cn += Cn[base + g]; }
    cgp[grp] = cp; cgn[grp] = cn;
  }
  __syncthreads();

  if (t < DSL) {
    float run = 0.f;
    for (int g2 = 0; g2 < NGRP; ++g2) { const float v = gn[g2][t]; gn[g2][t] = run; run += v; }
  } else if (t < 2 * DSL) {
    const int dd = t - DSL;
    float run = 0.f;
    for (int g2 = NGRP - 1; g2 >= 0; --g2) { const float v = gp[g2][dd]; gp[g2][dd] = run; run += v; }
  } else if (sl == 0 && t == 2 * DSL) {
    float run = 0.f;
    for (int g2 = 0; g2 < NGRP; ++g2) { const float v = cgn[g2]; cgn[g2] = run; run += v; }
  } else if (sl == 0 && t == 2 * DSL + 1) {
    float run = 0.f;
    for (int g2 = NGRP - 1; g2 >= 0; --g2) { const float v = cgp[g2]; cgp[g2] = run; run += v; }
  }
  __syncthreads();

  float runn = gn[grp][d4];
  for (int gg = 0; gg < GSZ; ++gg) {
    const int g = grp * GSZ + gg;
    BNeg[(base + g) * D + d] = runn;
    runn += Wn[(base + g) * D + d];
  }
  float runp = gp[grp][d4];
  for (int gg = GSZ - 1; gg >= 0; --gg) {
    const int g = grp * GSZ + gg;
    BPos[(base + g) * D + d] = runp;
    runp += Wp[(base + g) * D + d];
  }
  if (sl == 0 && d4 == 0) {
    float rn = cgn[grp];
    for (int gg = 0; gg < GSZ; ++gg) { const int g = grp * GSZ + gg; CnB[base + g] = rn; rn += Cn[base + g]; }
    float rp = cgp[grp];
    for (int gg = GSZ - 1; gg >= 0; --gg) { const int g = grp * GSZ + gg; CpB[base + g] = rp; rp += Cp[base + g]; }
  }
}

// ---------------- query: 32 lanes x float4 per row, branchless boundary loop ----------------
__global__ __launch_bounds__(256) void k_query(const float* __restrict__ f1,
                                               const float* __restrict__ f2s,
                                               const float* __restrict__ wps,
                                               const float* __restrict__ wns,
                                               const float* __restrict__ fts_s,
                                               const int* __restrict__ bstart,
                                               const float* __restrict__ BPos, const float* __restrict__ BNeg,
                                               const float* __restrict__ CpB, const float* __restrict__ CnB,
                                               const float* __restrict__ bias,
                                               float* __restrict__ out) {
  const int r = threadIdx.x >> 5;
  const int lane = threadIdx.x & 31;
  const int row = blockIdx.x * QROWS + r;
  const int b = row / N;
  const size_t bN = (size_t)b * N;
  const int d4 = lane * 4;
  const float f1v = f1[row];
  const float th = -f1v;
  const int g = bucket_of(th);
  const int base = bstart[b * (NB + 1) + g];
  const int end  = bstart[b * (NB + 1) + g + 1];
  float4 sn = *reinterpret_cast<const float4*>(&BNeg[((size_t)b * NB + g) * D + d4]);
  float4 sp = *reinterpret_cast<const float4*>(&BPos[((size_t)b * NB + g) * D + d4]);
  float cn = CnB[b * NB + g];
  float cp = CpB[b * NB + g];
  for (int e = base; e < end; ++e) {
    const float key = f2s[bN + e];
    const float wn_raw = wns[bN + e];
    const float wp_raw = wps[bN + e];
    const float4 v = *reinterpret_cast<const float4*>(&fts_s[(bN + e) * D + d4]);
    const bool neg = (key <= th);
    const float wn = neg ? wn_raw : 0.f;
    const float wp = neg ? 0.f : wp_raw;
    sn.x += wn * v.x; sn.y += wn * v.y; sn.z += wn * v.z; sn.w += wn * v.w;
    sp.x += wp * v.x; sp.y += wp * v.y; sp.z += wp * v.z; sp.w += wp * v.w;
    cn += wn; cp += wp;
  }
  const float wqp = expf(f1v), wqn = expf(ALPHA * f1v);
  const float denom = wqp * cp + wqn * cn;
  const float inv = 1.0f / denom;
  const float4 bi = *reinterpret_cast<const float4*>(&bias[d4]);
  float4 val;
  val.x = (wqp * sp.x + wqn * sn.x) * inv + bi.x;
  val.y = (wqp * sp.y + wqn * sn.y) * inv + bi.y;
  val.z = (wqp * sp.z + wqn * sn.z) * inv + bi.z;
  val.w = (wqp * sp.w + wqn * sn.w) * inv + bi.w;
  val.x = val.x >= 0.f ? val.x : ALPHA * val.x;
  val.y = val.y >= 0.f ? val.y : ALPHA * val.y;
  val.z = val.z >= 0.f ? val.z : ALPHA * val.z;
  val.w = val.w >= 0.f ? val.w : ALPHA * val.w;
  *reinterpret_cast<float4*>(&out[(size_t)row * D + d4]) = val;
}

extern "C" void kernel_launch(void* const* d_in, const int* in_sizes, int n_in,
                              void* d_out, int out_size, void* d_ws, size_t ws_size,
                              hipStream_t stream) {
  const float* seq  = (const float*)d_in[0];
  const float* Wf   = (const float*)d_in[1];
  const float* w1   = (const float*)d_in[2];
  const float* b1   = (const float*)d_in[3];
  const float* w2   = (const float*)d_in[4];
  const float* b2   = (const float*)d_in[5];
  const float* bias = (const float*)d_in[6];
  float* out = (float*)d_out;

  char* ws = (char*)d_ws;
  size_t off = 0;
  auto alloc = [&](size_t bytes) -> void* {
    void* p = ws + off;
    off = (off + bytes + 255) & ~(size_t)255;
    return p;
  };

  float* fts     = (float*)alloc((size_t)M * D * 4);
  float* fts_s   = (float*)alloc((size_t)M * D * 4);
  float* f1      = (float*)alloc((size_t)M * 4);
  float* f2      = (float*)alloc((size_t)M * 4);
  float* f2s     = (float*)alloc((size_t)M * 4);
  int*   idxs    = (int*)  alloc((size_t)M * 4);
  float* wps     = (float*)alloc((size_t)M * 4);
  float* wns     = (float*)alloc((size_t)M * 4);
  int*   bid     = (int*)  alloc((size_t)M * 4);
  int*   histcnt = (int*)  alloc((size_t)B * P * NB * 4);
  int*   substart= (int*)  alloc((size_t)B * P * NB * 4);
  int*   btot    = (int*)  alloc((size_t)B * NB * 4);
  int*   bstart  = (int*)  alloc((size_t)B * (NB + 1) * 4);
  float* Wp      = (float*)alloc((size_t)B * NB * D * 4);
  float* Wn      = (float*)alloc((size_t)B * NB * D * 4);
  float* Cp      = (float*)alloc((size_t)B * NB * 4);
  float* Cn      = (float*)alloc((size_t)B * NB * 4);
  float* BPos    = (float*)alloc((size_t)B * NB * D * 4);
  float* BNeg    = (float*)alloc((size_t)B * NB * D * 4);
  float* CpB     = (float*)alloc((size_t)B * NB * 4);
  float* CnB     = (float*)alloc((size_t)B * NB * 4);

  hipLaunchKernelGGL(k_gemm,  dim3(M / 64),          dim3(512), 0, stream, seq, Wf, w1, b1, w2, b2, fts, f1, f2);
  hipLaunchKernelGGL(k_hist,  dim3(B * P),           dim3(128), 0, stream, f2, bid, histcnt);
  hipLaunchKernelGGL(k_sub,   dim3(B * NB / 256),    dim3(256), 0, stream, histcnt, substart, btot);
  hipLaunchKernelGGL(k_scat,  dim3(B * P),           dim3(128), 0, stream, f2, bid, substart, btot, bstart,
                     f2s, idxs, wps, wns);
  hipLaunchKernelGGL(k_perm,  dim3(M * D / 4 / 256), dim3(256), 0, stream, fts, idxs, fts_s);
  hipLaunchKernelGGL(k_bsum,  dim3(B * NBB),         dim3(128), 0, stream, fts_s, wps, wns, bstart, Wp, Wn, Cp, Cn);
  hipLaunchKernelGGL(k_scan,  dim3(B * NSL),         dim3(256), 0, stream, Wp, Wn, Cp, Cn, BPos, BNeg, CpB, CnB);
  hipLaunchKernelGGL(k_query, dim3(M / QROWS),       dim3(256), 0, stream, f1, f2s, wps, wns, fts_s, bstart,
                     BPos, BNeg, CpB, CnB, bias, out);
}